// Round 7
// baseline (2726.230 us; speedup 1.0000x reference)
//
#include <hip/hip_runtime.h>
#include <hip/hip_bf16.h>
#include <hip/hip_fp16.h>
#include <math.h>

// Problem constants (match reference)
#define NN 100000
#define EE 1600000
#define HH 128
#define GG 2000
#define SS 200
#define CC 10
#define NPG 50   // nodes per graph
#define PGS 10   // graphs per set
#define NCLS 8             // XCD classes for scatter partitioning
#define CLSW 12500         // dst range width per class (100000/8)
#define BCAP 204800        // per-class bucket capacity (>> 200000 + 24 sigma)

typedef _Float16 f16x8 __attribute__((ext_vector_type(8)));
typedef float    f32x4 __attribute__((ext_vector_type(4)));

// ---------------- CSR build ----------------

__global__ void zero_int_kernel(int* p, int n) {
    int i = blockIdx.x * 256 + threadIdx.x;
    if (i < n) p[i] = 0;
}

__global__ void init_bins_kernel(int* bcur) {
    int i = threadIdx.x;
    if (i < NCLS) bcur[i] = i * BCAP;
}

// Pass A: bin edges by dst class. Wave-ballot append: one atomic per wave per
// class, lanes write consecutive slots. NT loads keep the stream out of L2.
__global__ __launch_bounds__(256) void bin_kernel(const int* __restrict__ ei,
                                                  int* __restrict__ bcur,
                                                  long long* __restrict__ ebin) {
    int idx = blockIdx.x * 256 + threadIdx.x;
    int s = __builtin_nontemporal_load(ei + idx);
    int d = __builtin_nontemporal_load(ei + EE + idx);
    int b = (int)((unsigned)d / CLSW);
    int lane = threadIdx.x & 63;
    long long pk = ((long long)d << 32) | (unsigned)s;
#pragma unroll
    for (int c = 0; c < NCLS; ++c) {
        unsigned long long m = __ballot(b == c);
        if (m == 0ull) continue;
        int leader = __ffsll((long long)m) - 1;
        int base = 0;
        if (lane == leader) base = atomicAdd(&bcur[c], (int)__popcll(m));
        base = __shfl(base, leader);
        if (b == c) {
            int pos = base + (int)__popcll(m & ((1ull << lane) - 1ull));
            ebin[pos] = pk;
        }
    }
}

// Pass B1: per-class degree count (class-pinned via bid&7 -> XCD-local atomics)
__global__ __launch_bounds__(256) void count_bin_kernel(const long long* __restrict__ ebin,
                                                        const int* __restrict__ bcur,
                                                        int* __restrict__ degi) {
    int cls = blockIdx.x & (NCLS - 1);
    int k = (blockIdx.x >> 3) * 256 + threadIdx.x;
    int cnt = bcur[cls] - cls * BCAP;
    if (k < cnt) {
        long long e = __builtin_nontemporal_load(ebin + cls * BCAP + k);
        int d = (int)(e >> 32);
        atomicAdd(&degi[d], 1);
    }
}

// per-chunk inclusive scan: row_ptr[i+1] = scan(degi)[i] within chunk; bsum[b] = chunk total
__global__ void scan_chunk_kernel(const int* __restrict__ v, int* __restrict__ row_ptr,
                                  int* __restrict__ bsum, int n) {
    __shared__ int s[256];
    int tid = threadIdx.x;
    int i = blockIdx.x * 256 + tid;
    int x = (i < n) ? v[i] : 0;
    s[tid] = x;
    __syncthreads();
    for (int off = 1; off < 256; off <<= 1) {
        int y = (tid >= off) ? s[tid - off] : 0;
        __syncthreads();
        s[tid] += y;
        __syncthreads();
    }
    if (i < n) row_ptr[i + 1] = s[tid];
    if (tid == 255) bsum[blockIdx.x] = s[255];
}

__global__ void scan_bsums_kernel(int* bsum, int nb) {
    __shared__ int s[512];
    int tid = threadIdx.x;
    int x = (tid < nb) ? bsum[tid] : 0;
    s[tid] = x;
    __syncthreads();
    for (int off = 1; off < 512; off <<= 1) {
        int y = (tid >= off) ? s[tid - off] : 0;
        __syncthreads();
        s[tid] += y;
        __syncthreads();
    }
    if (tid < nb) bsum[tid] = s[tid];
}

__global__ void scan_finish_kernel(int* __restrict__ row_ptr, const int* __restrict__ bsum, int n) {
    int i = blockIdx.x * 256 + threadIdx.x;
    if (i < n) {
        if (blockIdx.x > 0) row_ptr[i + 1] += bsum[blockIdx.x - 1];
    }
    if (i == 0) row_ptr[0] = 0;
}

// dinv + cursor init (cursor[i] = row_ptr[i], the exclusive start)
__global__ void dinv_kernel(const int* __restrict__ degi, const int* __restrict__ row_ptr,
                            float* __restrict__ dinv, int* __restrict__ cursor, int n) {
    int i = blockIdx.x * 256 + threadIdx.x;
    if (i < n) {
        dinv[i] = 1.0f / sqrtf((float)(degi[i] + 1));  // +1 self loop
        cursor[i] = row_ptr[i];
    }
}

// Pass B2: class-pinned CSR fill from bins. Each class reads only its own
// bucket (1.6MB) -> no L2 pollution; col/cursor lines stay XCD-local.
__global__ __launch_bounds__(256) void fill_bin_kernel(const long long* __restrict__ ebin,
                                                       const int* __restrict__ bcur,
                                                       int* __restrict__ cursor,
                                                       int* __restrict__ col) {
    int cls = blockIdx.x & (NCLS - 1);
    int k = (blockIdx.x >> 3) * 256 + threadIdx.x;
    int cnt = bcur[cls] - cls * BCAP;
    if (k < cnt) {
        long long e = __builtin_nontemporal_load(ebin + cls * BCAP + k);
        int s = (int)(e & 0xffffffffll);
        int d = (int)(e >> 32);
        int o = atomicAdd(&cursor[d], 1);
        col[o] = s;
    }
}

// ---------------- MFMA GEMM: Y[n][128](fp16, x dinv[row]) = X[n][128] @ W[128][128] ----------
// 128 rows/block, 4 waves; wave handles 32 rows (2 row-tiles of 16), 8 col-tiles, K=4x32.
// Wt: W transposed fp16 in LDS (pitch 136 halves -> 2-way-free b128 reads).
// Epilogue: stage fp16 output in LDS, write back fully coalesced 16B/lane.

#define WTP 136

template <bool IN32>
__global__ __launch_bounds__(256) void gemm_mfma_kernel(const void* __restrict__ Xv,
                                                        const float* __restrict__ W,
                                                        const float* __restrict__ dinv,
                                                        _Float16* __restrict__ Y, int nrows) {
    __shared__ _Float16 Wt[128][WTP];   // 34.8 KB
    __shared__ _Float16 Ob[128][WTP];   // 34.8 KB
    int tid = threadIdx.x;
    int row0 = blockIdx.x * 128;

    // stage W transposed as fp16
    const float4* W4 = (const float4*)W;
#pragma unroll
    for (int it = 0; it < 16; ++it) {
        int f = it * 256 + tid;      // float4 id in [0,4096)
        int k = f >> 5;              // W row
        int c = (f & 31) << 2;       // W col (x4)
        float4 v = W4[f];
        Wt[c + 0][k] = (_Float16)v.x;
        Wt[c + 1][k] = (_Float16)v.y;
        Wt[c + 2][k] = (_Float16)v.z;
        Wt[c + 3][k] = (_Float16)v.w;
    }
    __syncthreads();

    int wave = tid >> 6;
    int l = tid & 63;
    int arow = l & 15;
    int kg = l >> 4;                 // k-group 0..3
    int baseRow = row0 + wave * 32;

    // A fragments: lane holds X[row][ks*32 + kg*8 .. +8]
    f16x8 afrag[2][4];
#pragma unroll
    for (int rt = 0; rt < 2; ++rt) {
        int r = baseRow + rt * 16 + arow;
        r = min(r, nrows - 1);
        if (IN32) {
            const float* xr = ((const float*)Xv) + (size_t)r * 128;
#pragma unroll
            for (int ks = 0; ks < 4; ++ks) {
                int k0 = ks * 32 + kg * 8;
                float4 a = ((const float4*)xr)[k0 >> 2];
                float4 b = ((const float4*)xr)[(k0 >> 2) + 1];
                f16x8 v;
                v[0] = (_Float16)a.x; v[1] = (_Float16)a.y;
                v[2] = (_Float16)a.z; v[3] = (_Float16)a.w;
                v[4] = (_Float16)b.x; v[5] = (_Float16)b.y;
                v[6] = (_Float16)b.z; v[7] = (_Float16)b.w;
                afrag[rt][ks] = v;
            }
        } else {
            const f16x8* xr = (const f16x8*)(((const _Float16*)Xv) + (size_t)r * 128);
#pragma unroll
            for (int ks = 0; ks < 4; ++ks) afrag[rt][ks] = xr[ks * 4 + kg];
        }
    }

    f32x4 acc[2][8];
#pragma unroll
    for (int rt = 0; rt < 2; ++rt)
#pragma unroll
        for (int ct = 0; ct < 8; ++ct) acc[rt][ct] = (f32x4){0.f, 0.f, 0.f, 0.f};

#pragma unroll
    for (int ct = 0; ct < 8; ++ct) {
#pragma unroll
        for (int ks = 0; ks < 4; ++ks) {
            f16x8 b = *(const f16x8*)&Wt[ct * 16 + arow][ks * 32 + kg * 8];
            acc[0][ct] = __builtin_amdgcn_mfma_f32_16x16x32_f16(afrag[0][ks], b, acc[0][ct], 0, 0, 0);
            acc[1][ct] = __builtin_amdgcn_mfma_f32_16x16x32_f16(afrag[1][ks], b, acc[1][ct], 0, 0, 0);
        }
    }

    // dinv for the 8 rows this lane owns (D: row = rt*16 + 4*kg + j, col = arow)
    float dv[2][4];
#pragma unroll
    for (int rt = 0; rt < 2; ++rt)
#pragma unroll
        for (int j = 0; j < 4; ++j) {
            int r = baseRow + rt * 16 + 4 * kg + j;
            dv[rt][j] = dinv[min(r, nrows - 1)];
        }

    // stage to LDS (own wave's 32 rows only — no block sync needed)
#pragma unroll
    for (int rt = 0; rt < 2; ++rt)
#pragma unroll
        for (int ct = 0; ct < 8; ++ct)
#pragma unroll
            for (int j = 0; j < 4; ++j)
                Ob[wave * 32 + rt * 16 + 4 * kg + j][ct * 16 + arow] =
                    (_Float16)(acc[rt][ct][j] * dv[rt][j]);

    // coalesced write-back: 8 x 16B per lane
#pragma unroll
    for (int i = 0; i < 8; ++i) {
        int q = i * 64 + l;          // [0,512): 32 rows x 16 chunks
        int lrow = q >> 4;
        int c = q & 15;
        int r = baseRow + lrow;
        if (r < nrows) {
            f16x8 v = *(const f16x8*)&Ob[wave * 32 + lrow][c * 8];
            *(f16x8*)(Y + (size_t)r * 128 + c * 8) = v;
        }
    }
}

// ---------------- GCN aggregation: out = relu(dinv[i]*(sum hw'[col] + hw'[i]) + b), fp16 out --

__global__ __launch_bounds__(256) void aggregate_kernel(const __half* __restrict__ hw,
                                                        const int* __restrict__ rp,
                                                        const int* __restrict__ col,
                                                        const float* __restrict__ dinv,
                                                        const float* __restrict__ bias,
                                                        __half* __restrict__ outp, int n) {
    int wid = threadIdx.x >> 6;
    int lane = threadIdx.x & 63;
    int i = blockIdx.x * 4 + wid;
    if (i >= n) return;
    const __half2* hw2 = (const __half2*)hw;  // row = 64 half2 (256B)
    float2 a0, a1, a2, a3;
    {
        float2 self = __half22float2(hw2[(size_t)i * 64 + lane]);
        a0.x = self.x; a0.y = self.y;
    }
    a1 = make_float2(0.f, 0.f);
    a2 = make_float2(0.f, 0.f);
    a3 = make_float2(0.f, 0.f);
    int j0 = rp[i], j1 = rp[i + 1];
    int j = j0;
    for (; j + 8 <= j1; j += 8) {
        int s0 = col[j + 0];
        int s1 = col[j + 1];
        int s2 = col[j + 2];
        int s3 = col[j + 3];
        int s4 = col[j + 4];
        int s5 = col[j + 5];
        int s6 = col[j + 6];
        int s7 = col[j + 7];
        __half2 v0 = hw2[(size_t)s0 * 64 + lane];
        __half2 v1 = hw2[(size_t)s1 * 64 + lane];
        __half2 v2 = hw2[(size_t)s2 * 64 + lane];
        __half2 v3 = hw2[(size_t)s3 * 64 + lane];
        __half2 v4 = hw2[(size_t)s4 * 64 + lane];
        __half2 v5 = hw2[(size_t)s5 * 64 + lane];
        __half2 v6 = hw2[(size_t)s6 * 64 + lane];
        __half2 v7 = hw2[(size_t)s7 * 64 + lane];
        float2 f;
        f = __half22float2(v0); a0.x += f.x; a0.y += f.y;
        f = __half22float2(v1); a1.x += f.x; a1.y += f.y;
        f = __half22float2(v2); a2.x += f.x; a2.y += f.y;
        f = __half22float2(v3); a3.x += f.x; a3.y += f.y;
        f = __half22float2(v4); a0.x += f.x; a0.y += f.y;
        f = __half22float2(v5); a1.x += f.x; a1.y += f.y;
        f = __half22float2(v6); a2.x += f.x; a2.y += f.y;
        f = __half22float2(v7); a3.x += f.x; a3.y += f.y;
    }
    for (; j + 4 <= j1; j += 4) {
        int s0 = col[j + 0];
        int s1 = col[j + 1];
        int s2 = col[j + 2];
        int s3 = col[j + 3];
        __half2 v0 = hw2[(size_t)s0 * 64 + lane];
        __half2 v1 = hw2[(size_t)s1 * 64 + lane];
        __half2 v2 = hw2[(size_t)s2 * 64 + lane];
        __half2 v3 = hw2[(size_t)s3 * 64 + lane];
        float2 f;
        f = __half22float2(v0); a0.x += f.x; a0.y += f.y;
        f = __half22float2(v1); a1.x += f.x; a1.y += f.y;
        f = __half22float2(v2); a2.x += f.x; a2.y += f.y;
        f = __half22float2(v3); a3.x += f.x; a3.y += f.y;
    }
    for (; j < j1; ++j) {
        int s = col[j];
        float2 f = __half22float2(hw2[(size_t)s * 64 + lane]);
        a0.x += f.x; a0.y += f.y;
    }
    float di = dinv[i];
    float2 acc;
    acc.x = ((a0.x + a1.x) + (a2.x + a3.x)) * di;
    acc.y = ((a0.y + a1.y) + (a2.y + a3.y)) * di;
    float2 bv = ((const float2*)bias)[lane];
    float rx = fmaxf(acc.x + bv.x, 0.f);
    float ry = fmaxf(acc.y + bv.y, 0.f);
    ((__half2*)outp)[(size_t)i * 64 + lane] = __floats2half2_rn(rx, ry);
}

// ---------------- mean pool (50 consecutive fp16 rows per graph) ----------------

__global__ __launch_bounds__(256) void pool_kernel(const __half* __restrict__ h,
                                                   float* __restrict__ gemb) {
    int wid = threadIdx.x >> 6;
    int lane = threadIdx.x & 63;
    int g = blockIdx.x * 4 + wid;
    if (g >= GG) return;
    const __half2* h2 = (const __half2*)h;
    float2 acc = {0.f, 0.f};
    size_t base = (size_t)g * NPG * 64;
    for (int r = 0; r < NPG; ++r) {
        float2 v = __half22float2(h2[base + (size_t)r * 64 + lane]);
        acc.x += v.x;
        acc.y += v.y;
    }
    float2 o;
    o.x = acc.x / (float)NPG;
    o.y = acc.y / (float)NPG;
    ((float2*)gemb)[(size_t)g * 64 + lane] = o;
}

// ---------------- DeepSets psi: p_g = tanh(relu(emb W1 + b1) W2 + b2) ----------------

__global__ __launch_bounds__(128) void psi_kernel(const float* __restrict__ gemb,
                                                  const float* __restrict__ W1,
                                                  const float* __restrict__ b1,
                                                  const float* __restrict__ W2,
                                                  const float* __restrict__ b2,
                                                  float* __restrict__ pbuf) {
    __shared__ float e[128];
    __shared__ float t[128];
    int g = blockIdx.x;
    int c = threadIdx.x;
    e[c] = gemb[(size_t)g * 128 + c];
    __syncthreads();
    float acc = b1[c];
#pragma unroll 8
    for (int k = 0; k < 128; ++k) acc += e[k] * W1[k * 128 + c];
    t[c] = fmaxf(acc, 0.f);
    __syncthreads();
    float acc2 = b2[c];
#pragma unroll 8
    for (int k = 0; k < 128; ++k) acc2 += t[k] * W2[k * 128 + c];
    pbuf[(size_t)g * 128 + c] = tanhf(acc2);
}

// ---------------- set-sum + phi head ----------------

__global__ __launch_bounds__(128) void phi_kernel(const float* __restrict__ pbuf,
                                                  const float* __restrict__ W1,
                                                  const float* __restrict__ b1,
                                                  const float* __restrict__ W2,
                                                  const float* __restrict__ b2,
                                                  float* __restrict__ out) {
    __shared__ float a[128];
    __shared__ float u[128];
    int s = blockIdx.x;
    int c = threadIdx.x;
    float acc = 0.f;
#pragma unroll
    for (int p = 0; p < PGS; ++p) acc += pbuf[(size_t)(s + p * SS) * 128 + c];
    a[c] = acc;
    __syncthreads();
    float acc1 = b1[c];
#pragma unroll 8
    for (int k = 0; k < 128; ++k) acc1 += a[k] * W1[k * 128 + c];
    u[c] = fmaxf(acc1, 0.f);
    __syncthreads();
    if (c < CC) {
        float acc2 = b2[c];
#pragma unroll 8
        for (int k = 0; k < 128; ++k) acc2 += u[k] * W2[k * CC + c];
        out[(size_t)s * CC + c] = acc2;
    }
}

// ---------------- launch ----------------

extern "C" void kernel_launch(void* const* d_in, const int* in_sizes, int n_in,
                              void* d_out, int out_size, void* d_ws, size_t ws_size,
                              hipStream_t stream) {
    const float* x   = (const float*)d_in[0];
    const int* ei    = (const int*)d_in[1];
    const float* W1  = (const float*)d_in[4];
    const float* b1  = (const float*)d_in[5];
    const float* W2  = (const float*)d_in[6];
    const float* b2  = (const float*)d_in[7];
    const float* W3  = (const float*)d_in[8];
    const float* b3  = (const float*)d_in[9];
    const float* pW1 = (const float*)d_in[10];
    const float* pb1 = (const float*)d_in[11];
    const float* pW2 = (const float*)d_in[12];
    const float* pb2 = (const float*)d_in[13];
    const float* fW1 = (const float*)d_in[14];
    const float* fb1 = (const float*)d_in[15];
    const float* fW2 = (const float*)d_in[16];
    const float* fb2 = (const float*)d_in[17];
    float* out = (float*)d_out;

    // workspace carve-up (256B aligned)
    char* p = (char*)d_ws;
    auto alloc = [&](size_t bytes) {
        char* r = p;
        p += (bytes + 255) & ~(size_t)255;
        return r;
    };
    int*       degi    = (int*)alloc((size_t)NN * 4);
    float*     dinv    = (float*)alloc((size_t)NN * 4);
    int*       row_ptr = (int*)alloc((size_t)(NN + 1) * 4);
    int*       cursor  = (int*)alloc((size_t)NN * 4);
    int*       bsum    = (int*)alloc(512 * 4);
    int*       bcur    = (int*)alloc(NCLS * 4);
    int*       col     = (int*)alloc((size_t)EE * 4);
    long long* ebin    = (long long*)alloc((size_t)NCLS * BCAP * 8);  // 13.1 MB
    _Float16*  bufA    = (_Float16*)alloc((size_t)NN * HH * 2);  // dinv-scaled XW (gather operand)
    __half*    bufB    = (__half*)alloc((size_t)NN * HH * 2);    // relu'd layer output
    float*     gemb    = (float*)alloc((size_t)GG * HH * 4);
    float*     pbuf    = (float*)alloc((size_t)GG * HH * 4);

    const int nblkN = (NN + 255) / 256;        // 391
    const int nblkE = (EE + 255) / 256;        // 6250
    const int binBlocks = NCLS * (BCAP / 256); // 8 * 800 = 6400

    // CSR build (two-pass binned)
    zero_int_kernel<<<nblkN, 256, 0, stream>>>(degi, NN);
    init_bins_kernel<<<1, 64, 0, stream>>>(bcur);
    bin_kernel<<<nblkE, 256, 0, stream>>>(ei, bcur, ebin);
    count_bin_kernel<<<binBlocks, 256, 0, stream>>>(ebin, bcur, degi);
    scan_chunk_kernel<<<nblkN, 256, 0, stream>>>(degi, row_ptr, bsum, NN);
    scan_bsums_kernel<<<1, 512, 0, stream>>>(bsum, nblkN);
    scan_finish_kernel<<<nblkN, 256, 0, stream>>>(row_ptr, bsum, NN);
    dinv_kernel<<<nblkN, 256, 0, stream>>>(degi, row_ptr, dinv, cursor, NN);
    fill_bin_kernel<<<binBlocks, 256, 0, stream>>>(ebin, bcur, cursor, col);

    const int gemmBlocks = (NN + 127) / 128;   // 782
    const int aggBlocks  = (NN + 3) / 4;       // 25000

    // layer 1
    gemm_mfma_kernel<true><<<gemmBlocks, 256, 0, stream>>>(x, W1, dinv, bufA, NN);
    aggregate_kernel<<<aggBlocks, 256, 0, stream>>>((const __half*)bufA, row_ptr, col, dinv, b1, bufB, NN);
    // layer 2
    gemm_mfma_kernel<false><<<gemmBlocks, 256, 0, stream>>>(bufB, W2, dinv, bufA, NN);
    aggregate_kernel<<<aggBlocks, 256, 0, stream>>>((const __half*)bufA, row_ptr, col, dinv, b2, bufB, NN);
    // layer 3
    gemm_mfma_kernel<false><<<gemmBlocks, 256, 0, stream>>>(bufB, W3, dinv, bufA, NN);
    aggregate_kernel<<<aggBlocks, 256, 0, stream>>>((const __half*)bufA, row_ptr, col, dinv, b3, bufB, NN);

    // pool -> [G,H]
    pool_kernel<<<(GG + 3) / 4, 256, 0, stream>>>(bufB, gemb);
    // DeepSets
    psi_kernel<<<GG, 128, 0, stream>>>(gemb, pW1, pb1, pW2, pb2, pbuf);
    phi_kernel<<<SS, 128, 0, stream>>>(pbuf, fW1, fb1, fW2, fb2, out);
}

// Round 8
// 468.478 us; speedup vs baseline: 5.8193x; 5.8193x over previous
//
#include <hip/hip_runtime.h>
#include <hip/hip_bf16.h>
#include <hip/hip_fp16.h>
#include <math.h>

// Problem constants (match reference)
#define NN 100000
#define EE 1600000
#define HH 128
#define GG 2000
#define SS 200
#define CC 10
#define NPG 50   // nodes per graph
#define PGS 10   // graphs per set
#define NCLS 8             // XCD classes for scatter partitioning
#define CLSW 12500         // dst range width per class (100000/8)
#define EPB 2048           // edges per histogram/scatter block
#define NBLKH 782          // ceil(EE/EPB)
#define SCAN_N (NCLS * NBLKH)   // 6256
#define CMAXBLK 816        // blocks per class in count/fill (816*256=208896 >= 200000+21sigma)

typedef _Float16 f16x8 __attribute__((ext_vector_type(8)));
typedef float    f32x4 __attribute__((ext_vector_type(4)));

// ---------------- CSR build (deterministic binned, no global atomics in binning) -------------

__global__ void zero_int_kernel(int* p, int n) {
    int i = blockIdx.x * 256 + threadIdx.x;
    if (i < n) p[i] = 0;
}

// Step 1: per-block per-class histogram (LDS only)
__global__ __launch_bounds__(256) void histo_kernel(const int* __restrict__ ei_dst,
                                                    int* __restrict__ blkcnt) {
    __shared__ int h[4][8];
    if (threadIdx.x < 32) ((int*)h)[threadIdx.x] = 0;
    __syncthreads();
    int w = threadIdx.x >> 6;
    int base = blockIdx.x * EPB;
#pragma unroll
    for (int i = 0; i < 8; ++i) {
        int idx = base + i * 256 + threadIdx.x;
        if (idx < EE) {
            int d = __builtin_nontemporal_load(ei_dst + idx);
            atomicAdd(&h[w][(unsigned)d / CLSW], 1);
        }
    }
    __syncthreads();
    if (threadIdx.x < 8) {
        int c = threadIdx.x;
        blkcnt[c * NBLKH + blockIdx.x] = h[0][c] + h[1][c] + h[2][c] + h[3][c];
    }
}

// Step 2: exclusive scan of class-major blkcnt -> blkoff; class boundaries -> cstart[0..8]
__global__ __launch_bounds__(256) void scan_offsets_kernel(const int* __restrict__ blkcnt,
                                                           int* __restrict__ blkoff,
                                                           int* __restrict__ cstart) {
    __shared__ int tot[256];
    __shared__ int ls[256 * 25];
    int t = threadIdx.x;
    int s = 0;
#pragma unroll
    for (int i = 0; i < 25; ++i) {
        int idx = t * 25 + i;
        int v = (idx < SCAN_N) ? blkcnt[idx] : 0;
        ls[t * 25 + i] = s;
        s += v;
    }
    tot[t] = s;
    __syncthreads();
    for (int off = 1; off < 256; off <<= 1) {
        int y = (t >= off) ? tot[t - off] : 0;
        __syncthreads();
        tot[t] += y;
        __syncthreads();
    }
    int add = (t > 0) ? tot[t - 1] : 0;
#pragma unroll
    for (int i = 0; i < 25; ++i) {
        int idx = t * 25 + i;
        if (idx < SCAN_N) blkoff[idx] = ls[t * 25 + i] + add;
    }
    __syncthreads();
    if (t < 8) {
        // exclusive prefix at class start: recompute from LDS-scanned values
        int idx = t * NBLKH;
        int chunk = idx / 25, off = idx % 25;
        cstart[t] = ls[chunk * 25 + off] + ((chunk > 0) ? tot[chunk - 1] : 0);
    }
    if (t == 255) cstart[8] = tot[255];
}

// Step 3: scatter edges into packed class buckets (LDS cursors, no global atomics)
__global__ __launch_bounds__(256) void scatter_bin_kernel(const int* __restrict__ ei,
                                                          const int* __restrict__ blkoff,
                                                          long long* __restrict__ ebin) {
    __shared__ int cur[8];
    if (threadIdx.x < 8) cur[threadIdx.x] = blkoff[threadIdx.x * NBLKH + blockIdx.x];
    __syncthreads();
    int base = blockIdx.x * EPB;
#pragma unroll
    for (int i = 0; i < 8; ++i) {
        int idx = base + i * 256 + threadIdx.x;
        if (idx < EE) {
            int s = __builtin_nontemporal_load(ei + idx);
            int d = __builtin_nontemporal_load(ei + EE + idx);
            int c = (unsigned)d / CLSW;
            int pos = atomicAdd(&cur[c], 1);
            ebin[pos] = ((long long)d << 32) | (unsigned)s;
        }
    }
}

// Step 4: per-class degree count (class-pinned via bid&7 -> XCD-local lines)
__global__ __launch_bounds__(256) void count_bin_kernel(const long long* __restrict__ ebin,
                                                        const int* __restrict__ cstart,
                                                        int* __restrict__ degi) {
    int cls = blockIdx.x & (NCLS - 1);
    int k = (blockIdx.x >> 3) * 256 + threadIdx.x;
    int beg = cstart[cls], end = cstart[cls + 1];
    if (k < end - beg) {
        long long e = __builtin_nontemporal_load(ebin + beg + k);
        atomicAdd(&degi[(int)(e >> 32)], 1);
    }
}

// per-chunk inclusive scan: row_ptr[i+1] = scan(degi)[i] within chunk; bsum[b] = chunk total
__global__ void scan_chunk_kernel(const int* __restrict__ v, int* __restrict__ row_ptr,
                                  int* __restrict__ bsum, int n) {
    __shared__ int s[256];
    int tid = threadIdx.x;
    int i = blockIdx.x * 256 + tid;
    int x = (i < n) ? v[i] : 0;
    s[tid] = x;
    __syncthreads();
    for (int off = 1; off < 256; off <<= 1) {
        int y = (tid >= off) ? s[tid - off] : 0;
        __syncthreads();
        s[tid] += y;
        __syncthreads();
    }
    if (i < n) row_ptr[i + 1] = s[tid];
    if (tid == 255) bsum[blockIdx.x] = s[255];
}

__global__ void scan_bsums_kernel(int* bsum, int nb) {
    __shared__ int s[512];
    int tid = threadIdx.x;
    int x = (tid < nb) ? bsum[tid] : 0;
    s[tid] = x;
    __syncthreads();
    for (int off = 1; off < 512; off <<= 1) {
        int y = (tid >= off) ? s[tid - off] : 0;
        __syncthreads();
        s[tid] += y;
        __syncthreads();
    }
    if (tid < nb) bsum[tid] = s[tid];
}

__global__ void scan_finish_kernel(int* __restrict__ row_ptr, const int* __restrict__ bsum, int n) {
    int i = blockIdx.x * 256 + threadIdx.x;
    if (i < n) {
        if (blockIdx.x > 0) row_ptr[i + 1] += bsum[blockIdx.x - 1];
    }
    if (i == 0) row_ptr[0] = 0;
}

// dinv + cursor init (cursor[i] = row_ptr[i], the exclusive start)
__global__ void dinv_kernel(const int* __restrict__ degi, const int* __restrict__ row_ptr,
                            float* __restrict__ dinv, int* __restrict__ cursor, int n) {
    int i = blockIdx.x * 256 + threadIdx.x;
    if (i < n) {
        dinv[i] = 1.0f / sqrtf((float)(degi[i] + 1));  // +1 self loop
        cursor[i] = row_ptr[i];
    }
}

// Step 5: class-pinned CSR fill from packed buckets
__global__ __launch_bounds__(256) void fill_bin_kernel(const long long* __restrict__ ebin,
                                                       const int* __restrict__ cstart,
                                                       int* __restrict__ cursor,
                                                       int* __restrict__ col) {
    int cls = blockIdx.x & (NCLS - 1);
    int k = (blockIdx.x >> 3) * 256 + threadIdx.x;
    int beg = cstart[cls], end = cstart[cls + 1];
    if (k < end - beg) {
        long long e = __builtin_nontemporal_load(ebin + beg + k);
        int s = (int)(e & 0xffffffffll);
        int d = (int)(e >> 32);
        int o = atomicAdd(&cursor[d], 1);
        col[o] = s;
    }
}

// ---------------- MFMA GEMM: Y[n][128](fp16, x dinv[row]) = X[n][128] @ W[128][128] ----------

#define WTP 136

template <bool IN32>
__global__ __launch_bounds__(256) void gemm_mfma_kernel(const void* __restrict__ Xv,
                                                        const float* __restrict__ W,
                                                        const float* __restrict__ dinv,
                                                        _Float16* __restrict__ Y, int nrows) {
    __shared__ _Float16 Wt[128][WTP];   // 34.8 KB
    __shared__ _Float16 Ob[128][WTP];   // 34.8 KB
    int tid = threadIdx.x;
    int row0 = blockIdx.x * 128;

    // stage W transposed as fp16
    const float4* W4 = (const float4*)W;
#pragma unroll
    for (int it = 0; it < 16; ++it) {
        int f = it * 256 + tid;      // float4 id in [0,4096)
        int k = f >> 5;              // W row
        int c = (f & 31) << 2;       // W col (x4)
        float4 v = W4[f];
        Wt[c + 0][k] = (_Float16)v.x;
        Wt[c + 1][k] = (_Float16)v.y;
        Wt[c + 2][k] = (_Float16)v.z;
        Wt[c + 3][k] = (_Float16)v.w;
    }
    __syncthreads();

    int wave = tid >> 6;
    int l = tid & 63;
    int arow = l & 15;
    int kg = l >> 4;                 // k-group 0..3
    int baseRow = row0 + wave * 32;

    // A fragments: lane holds X[row][ks*32 + kg*8 .. +8]
    f16x8 afrag[2][4];
#pragma unroll
    for (int rt = 0; rt < 2; ++rt) {
        int r = baseRow + rt * 16 + arow;
        r = min(r, nrows - 1);
        if (IN32) {
            const float* xr = ((const float*)Xv) + (size_t)r * 128;
#pragma unroll
            for (int ks = 0; ks < 4; ++ks) {
                int k0 = ks * 32 + kg * 8;
                float4 a = ((const float4*)xr)[k0 >> 2];
                float4 b = ((const float4*)xr)[(k0 >> 2) + 1];
                f16x8 v;
                v[0] = (_Float16)a.x; v[1] = (_Float16)a.y;
                v[2] = (_Float16)a.z; v[3] = (_Float16)a.w;
                v[4] = (_Float16)b.x; v[5] = (_Float16)b.y;
                v[6] = (_Float16)b.z; v[7] = (_Float16)b.w;
                afrag[rt][ks] = v;
            }
        } else {
            const f16x8* xr = (const f16x8*)(((const _Float16*)Xv) + (size_t)r * 128);
#pragma unroll
            for (int ks = 0; ks < 4; ++ks) afrag[rt][ks] = xr[ks * 4 + kg];
        }
    }

    f32x4 acc[2][8];
#pragma unroll
    for (int rt = 0; rt < 2; ++rt)
#pragma unroll
        for (int ct = 0; ct < 8; ++ct) acc[rt][ct] = (f32x4){0.f, 0.f, 0.f, 0.f};

#pragma unroll
    for (int ct = 0; ct < 8; ++ct) {
#pragma unroll
        for (int ks = 0; ks < 4; ++ks) {
            f16x8 b = *(const f16x8*)&Wt[ct * 16 + arow][ks * 32 + kg * 8];
            acc[0][ct] = __builtin_amdgcn_mfma_f32_16x16x32_f16(afrag[0][ks], b, acc[0][ct], 0, 0, 0);
            acc[1][ct] = __builtin_amdgcn_mfma_f32_16x16x32_f16(afrag[1][ks], b, acc[1][ct], 0, 0, 0);
        }
    }

    // dinv for the 8 rows this lane owns (D: row = rt*16 + 4*kg + j, col = arow)
    float dv[2][4];
#pragma unroll
    for (int rt = 0; rt < 2; ++rt)
#pragma unroll
        for (int j = 0; j < 4; ++j) {
            int r = baseRow + rt * 16 + 4 * kg + j;
            dv[rt][j] = dinv[min(r, nrows - 1)];
        }

    // stage to LDS (own wave's 32 rows only — no block sync needed)
#pragma unroll
    for (int rt = 0; rt < 2; ++rt)
#pragma unroll
        for (int ct = 0; ct < 8; ++ct)
#pragma unroll
            for (int j = 0; j < 4; ++j)
                Ob[wave * 32 + rt * 16 + 4 * kg + j][ct * 16 + arow] =
                    (_Float16)(acc[rt][ct][j] * dv[rt][j]);

    // coalesced write-back: 8 x 16B per lane
#pragma unroll
    for (int i = 0; i < 8; ++i) {
        int q = i * 64 + l;          // [0,512): 32 rows x 16 chunks
        int lrow = q >> 4;
        int c = q & 15;
        int r = baseRow + lrow;
        if (r < nrows) {
            f16x8 v = *(const f16x8*)&Ob[wave * 32 + lrow][c * 8];
            *(f16x8*)(Y + (size_t)r * 128 + c * 8) = v;
        }
    }
}

// ---------------- GCN aggregation: out = relu(dinv[i]*(sum hw'[col] + hw'[i]) + b), fp16 out --

__global__ __launch_bounds__(256) void aggregate_kernel(const __half* __restrict__ hw,
                                                        const int* __restrict__ rp,
                                                        const int* __restrict__ col,
                                                        const float* __restrict__ dinv,
                                                        const float* __restrict__ bias,
                                                        __half* __restrict__ outp, int n) {
    int wid = threadIdx.x >> 6;
    int lane = threadIdx.x & 63;
    int i = blockIdx.x * 4 + wid;
    if (i >= n) return;
    const __half2* hw2 = (const __half2*)hw;  // row = 64 half2 (256B)
    float2 a0, a1, a2, a3;
    {
        float2 self = __half22float2(hw2[(size_t)i * 64 + lane]);
        a0.x = self.x; a0.y = self.y;
    }
    a1 = make_float2(0.f, 0.f);
    a2 = make_float2(0.f, 0.f);
    a3 = make_float2(0.f, 0.f);
    int j0 = rp[i], j1 = rp[i + 1];
    int j = j0;
    for (; j + 8 <= j1; j += 8) {
        int s0 = col[j + 0];
        int s1 = col[j + 1];
        int s2 = col[j + 2];
        int s3 = col[j + 3];
        int s4 = col[j + 4];
        int s5 = col[j + 5];
        int s6 = col[j + 6];
        int s7 = col[j + 7];
        __half2 v0 = hw2[(size_t)s0 * 64 + lane];
        __half2 v1 = hw2[(size_t)s1 * 64 + lane];
        __half2 v2 = hw2[(size_t)s2 * 64 + lane];
        __half2 v3 = hw2[(size_t)s3 * 64 + lane];
        __half2 v4 = hw2[(size_t)s4 * 64 + lane];
        __half2 v5 = hw2[(size_t)s5 * 64 + lane];
        __half2 v6 = hw2[(size_t)s6 * 64 + lane];
        __half2 v7 = hw2[(size_t)s7 * 64 + lane];
        float2 f;
        f = __half22float2(v0); a0.x += f.x; a0.y += f.y;
        f = __half22float2(v1); a1.x += f.x; a1.y += f.y;
        f = __half22float2(v2); a2.x += f.x; a2.y += f.y;
        f = __half22float2(v3); a3.x += f.x; a3.y += f.y;
        f = __half22float2(v4); a0.x += f.x; a0.y += f.y;
        f = __half22float2(v5); a1.x += f.x; a1.y += f.y;
        f = __half22float2(v6); a2.x += f.x; a2.y += f.y;
        f = __half22float2(v7); a3.x += f.x; a3.y += f.y;
    }
    for (; j + 4 <= j1; j += 4) {
        int s0 = col[j + 0];
        int s1 = col[j + 1];
        int s2 = col[j + 2];
        int s3 = col[j + 3];
        __half2 v0 = hw2[(size_t)s0 * 64 + lane];
        __half2 v1 = hw2[(size_t)s1 * 64 + lane];
        __half2 v2 = hw2[(size_t)s2 * 64 + lane];
        __half2 v3 = hw2[(size_t)s3 * 64 + lane];
        float2 f;
        f = __half22float2(v0); a0.x += f.x; a0.y += f.y;
        f = __half22float2(v1); a1.x += f.x; a1.y += f.y;
        f = __half22float2(v2); a2.x += f.x; a2.y += f.y;
        f = __half22float2(v3); a3.x += f.x; a3.y += f.y;
    }
    for (; j < j1; ++j) {
        int s = col[j];
        float2 f = __half22float2(hw2[(size_t)s * 64 + lane]);
        a0.x += f.x; a0.y += f.y;
    }
    float di = dinv[i];
    float2 acc;
    acc.x = ((a0.x + a1.x) + (a2.x + a3.x)) * di;
    acc.y = ((a0.y + a1.y) + (a2.y + a3.y)) * di;
    float2 bv = ((const float2*)bias)[lane];
    float rx = fmaxf(acc.x + bv.x, 0.f);
    float ry = fmaxf(acc.y + bv.y, 0.f);
    ((__half2*)outp)[(size_t)i * 64 + lane] = __floats2half2_rn(rx, ry);
}

// ---------------- mean pool (50 consecutive fp16 rows per graph) ----------------

__global__ __launch_bounds__(256) void pool_kernel(const __half* __restrict__ h,
                                                   float* __restrict__ gemb) {
    int wid = threadIdx.x >> 6;
    int lane = threadIdx.x & 63;
    int g = blockIdx.x * 4 + wid;
    if (g >= GG) return;
    const __half2* h2 = (const __half2*)h;
    float2 acc = {0.f, 0.f};
    size_t base = (size_t)g * NPG * 64;
    for (int r = 0; r < NPG; ++r) {
        float2 v = __half22float2(h2[base + (size_t)r * 64 + lane]);
        acc.x += v.x;
        acc.y += v.y;
    }
    float2 o;
    o.x = acc.x / (float)NPG;
    o.y = acc.y / (float)NPG;
    ((float2*)gemb)[(size_t)g * 64 + lane] = o;
}

// ---------------- DeepSets psi: p_g = tanh(relu(emb W1 + b1) W2 + b2) ----------------

__global__ __launch_bounds__(128) void psi_kernel(const float* __restrict__ gemb,
                                                  const float* __restrict__ W1,
                                                  const float* __restrict__ b1,
                                                  const float* __restrict__ W2,
                                                  const float* __restrict__ b2,
                                                  float* __restrict__ pbuf) {
    __shared__ float e[128];
    __shared__ float t[128];
    int g = blockIdx.x;
    int c = threadIdx.x;
    e[c] = gemb[(size_t)g * 128 + c];
    __syncthreads();
    float acc = b1[c];
#pragma unroll 8
    for (int k = 0; k < 128; ++k) acc += e[k] * W1[k * 128 + c];
    t[c] = fmaxf(acc, 0.f);
    __syncthreads();
    float acc2 = b2[c];
#pragma unroll 8
    for (int k = 0; k < 128; ++k) acc2 += t[k] * W2[k * 128 + c];
    pbuf[(size_t)g * 128 + c] = tanhf(acc2);
}

// ---------------- set-sum + phi head ----------------

__global__ __launch_bounds__(128) void phi_kernel(const float* __restrict__ pbuf,
                                                  const float* __restrict__ W1,
                                                  const float* __restrict__ b1,
                                                  const float* __restrict__ W2,
                                                  const float* __restrict__ b2,
                                                  float* __restrict__ out) {
    __shared__ float a[128];
    __shared__ float u[128];
    int s = blockIdx.x;
    int c = threadIdx.x;
    float acc = 0.f;
#pragma unroll
    for (int p = 0; p < PGS; ++p) acc += pbuf[(size_t)(s + p * SS) * 128 + c];
    a[c] = acc;
    __syncthreads();
    float acc1 = b1[c];
#pragma unroll 8
    for (int k = 0; k < 128; ++k) acc1 += a[k] * W1[k * 128 + c];
    u[c] = fmaxf(acc1, 0.f);
    __syncthreads();
    if (c < CC) {
        float acc2 = b2[c];
#pragma unroll 8
        for (int k = 0; k < 128; ++k) acc2 += u[k] * W2[k * CC + c];
        out[(size_t)s * CC + c] = acc2;
    }
}

// ---------------- launch ----------------

extern "C" void kernel_launch(void* const* d_in, const int* in_sizes, int n_in,
                              void* d_out, int out_size, void* d_ws, size_t ws_size,
                              hipStream_t stream) {
    const float* x   = (const float*)d_in[0];
    const int* ei    = (const int*)d_in[1];
    const float* W1  = (const float*)d_in[4];
    const float* b1  = (const float*)d_in[5];
    const float* W2  = (const float*)d_in[6];
    const float* b2  = (const float*)d_in[7];
    const float* W3  = (const float*)d_in[8];
    const float* b3  = (const float*)d_in[9];
    const float* pW1 = (const float*)d_in[10];
    const float* pb1 = (const float*)d_in[11];
    const float* pW2 = (const float*)d_in[12];
    const float* pb2 = (const float*)d_in[13];
    const float* fW1 = (const float*)d_in[14];
    const float* fb1 = (const float*)d_in[15];
    const float* fW2 = (const float*)d_in[16];
    const float* fb2 = (const float*)d_in[17];
    float* out = (float*)d_out;

    // workspace carve-up (256B aligned)
    char* p = (char*)d_ws;
    auto alloc = [&](size_t bytes) {
        char* r = p;
        p += (bytes + 255) & ~(size_t)255;
        return r;
    };
    int*       degi    = (int*)alloc((size_t)NN * 4);
    float*     dinv    = (float*)alloc((size_t)NN * 4);
    int*       row_ptr = (int*)alloc((size_t)(NN + 1) * 4);
    int*       cursor  = (int*)alloc((size_t)NN * 4);
    int*       bsum    = (int*)alloc(512 * 4);
    int*       blkcnt  = (int*)alloc((size_t)SCAN_N * 4);
    int*       blkoff  = (int*)alloc((size_t)SCAN_N * 4);
    int*       cstart  = (int*)alloc(16 * 4);
    int*       col     = (int*)alloc((size_t)EE * 4);
    long long* ebin    = (long long*)alloc((size_t)EE * 8);      // 12.8 MB packed buckets
    _Float16*  bufA    = (_Float16*)alloc((size_t)NN * HH * 2);  // dinv-scaled XW (gather operand)
    __half*    bufB    = (__half*)alloc((size_t)NN * HH * 2);    // relu'd layer output
    float*     gemb    = (float*)alloc((size_t)GG * HH * 4);
    float*     pbuf    = (float*)alloc((size_t)GG * HH * 4);

    const int nblkN = (NN + 255) / 256;        // 391
    const int binBlocks = NCLS * CMAXBLK;      // 6528

    // CSR build (deterministic binned)
    zero_int_kernel<<<nblkN, 256, 0, stream>>>(degi, NN);
    histo_kernel<<<NBLKH, 256, 0, stream>>>(ei + EE, blkcnt);
    scan_offsets_kernel<<<1, 256, 0, stream>>>(blkcnt, blkoff, cstart);
    scatter_bin_kernel<<<NBLKH, 256, 0, stream>>>(ei, blkoff, ebin);
    count_bin_kernel<<<binBlocks, 256, 0, stream>>>(ebin, cstart, degi);
    scan_chunk_kernel<<<nblkN, 256, 0, stream>>>(degi, row_ptr, bsum, NN);
    scan_bsums_kernel<<<1, 512, 0, stream>>>(bsum, nblkN);
    scan_finish_kernel<<<nblkN, 256, 0, stream>>>(row_ptr, bsum, NN);
    dinv_kernel<<<nblkN, 256, 0, stream>>>(degi, row_ptr, dinv, cursor, NN);
    fill_bin_kernel<<<binBlocks, 256, 0, stream>>>(ebin, cstart, cursor, col);

    const int gemmBlocks = (NN + 127) / 128;   // 782
    const int aggBlocks  = (NN + 3) / 4;       // 25000

    // layer 1
    gemm_mfma_kernel<true><<<gemmBlocks, 256, 0, stream>>>(x, W1, dinv, bufA, NN);
    aggregate_kernel<<<aggBlocks, 256, 0, stream>>>((const __half*)bufA, row_ptr, col, dinv, b1, bufB, NN);
    // layer 2
    gemm_mfma_kernel<false><<<gemmBlocks, 256, 0, stream>>>(bufB, W2, dinv, bufA, NN);
    aggregate_kernel<<<aggBlocks, 256, 0, stream>>>((const __half*)bufA, row_ptr, col, dinv, b2, bufB, NN);
    // layer 3
    gemm_mfma_kernel<false><<<gemmBlocks, 256, 0, stream>>>(bufB, W3, dinv, bufA, NN);
    aggregate_kernel<<<aggBlocks, 256, 0, stream>>>((const __half*)bufA, row_ptr, col, dinv, b3, bufB, NN);

    // pool -> [G,H]
    pool_kernel<<<(GG + 3) / 4, 256, 0, stream>>>(bufB, gemb);
    // DeepSets
    psi_kernel<<<GG, 128, 0, stream>>>(gemb, pW1, pb1, pW2, pb2, pbuf);
    phi_kernel<<<SS, 128, 0, stream>>>(pbuf, fW1, fb1, fW2, fb2, out);
}